// Round 2
// baseline (57.740 us; speedup 1.0000x reference)
//
#include <hip/hip_runtime.h>
#include <cstdint>
#include <cstddef>

typedef __attribute__((ext_vector_type(8))) short short8;
typedef __attribute__((ext_vector_type(4))) short short4_t;
typedef __attribute__((ext_vector_type(4))) float f32x4;

#define NF 40
#define NK 780           // 40*39/2 pairs
#define NPAIR 390        // NK/2
#define BT 16            // batch rows per block
#define THREADS 512      // 8 waves

__device__ __forceinline__ unsigned short f2bf(float f) {
    unsigned int u = __float_as_uint(f);
    u = (u + 0x7fffu + ((u >> 16) & 1u)) >> 16;
    return (unsigned short)u;
}
__device__ __forceinline__ float bf2f(short x) {
    return __uint_as_float(((unsigned int)(unsigned short)x) << 16);
}

// Pre-pass: wfrag[k][half][l][t] = bf16( W[k][ 8*(l>>4)+t ][ (l&15) + 16*half ] )
// = A-fragment (rows f, k-dim e) for mfma_f32_16x16x32_bf16; half selects f 0..15 / 16..31.
// (k-ordering within a lane is the same assumption for A and B, so any deviation from the
//  true HW ordering cancels in the dot product.)
__global__ __launch_bounds__(128) void wprep_kernel(const float* __restrict__ W,
                                                    unsigned short* __restrict__ wfrag) {
    __shared__ float wk[1024];
    const int k = blockIdx.x, t = threadIdx.x;
    const float4* src = (const float4*)(W + (size_t)k * 1024);
    float4* dst = (float4*)wk;
    dst[t] = src[t];
    dst[t + 128] = src[t + 128];
    __syncthreads();
    const int half = t >> 6, l = t & 63;
    const int f = (l & 15) + 16 * half;
    const int e0 = 8 * (l >> 4);
    short8 v;
#pragma unroll
    for (int tt = 0; tt < 8; ++tt) v[tt] = (short)f2bf(wk[(e0 + tt) * 32 + f]);
    *(short8*)(wfrag + (size_t)k * 1024 + half * 512 + l * 8) = v;
}

// Main kernel: one block = 16 batch rows x all 780 pairs; 8 waves split the 390 pair-pairs.
__global__ __launch_bounds__(THREADS) void bil_kernel(const float* __restrict__ emb,
                                                      const unsigned short* __restrict__ wfrag,
                                                      float* __restrict__ out) {
    // embT[field][lane'][t'] (bf16): element emb[b0 + (lane'&15)][field][8*(lane'>>4) + t']
    __shared__ __align__(16) char embT[NF * 1024];      // 40960 B
    __shared__ unsigned int ijA[NK];                    // 3120 B

    const int tid = threadIdx.x;
    const int b0 = blockIdx.x * BT;

    // --- Stage embedding tile (coalesced f32 reads, bf16 fragment-layout LDS writes) ---
    for (int u = tid; u < BT * 320; u += THREADS) {     // 320 float4 per row
        const int r = u / 320;
        const int c = u - 320 * r;
        const float4 x = *(const float4*)(emb + (size_t)(b0 + r) * (NF * 32) + 4 * c);
        const int field = c >> 3;
        const int lp = r + 16 * ((c & 7) >> 1);
        short4_t v;
        v[0] = (short)f2bf(x.x); v[1] = (short)f2bf(x.y);
        v[2] = (short)f2bf(x.z); v[3] = (short)f2bf(x.w);
        *(short4_t*)(embT + field * 1024 + lp * 16 + (c & 1) * 8) = v;
    }
    // --- Pair table: ij[k] = (j<<16) | i, triu_indices(40,1) i-major order ---
    for (int idx = tid; idx < NK; idx += THREADS) {
        int kk = idx, i = 0, len = 39;
        while (kk >= len) { kk -= len; ++i; --len; }
        ijA[idx] = ((unsigned)(i + 1 + kk) << 16) | (unsigned)i;
    }
    __syncthreads();

    const int w = tid >> 6;
    const int l = tid & 63;
    const int b = l & 15;
    const int h = l >> 4;

    // Contiguous pair-pair range per wave (each covers k = 2*pp, 2*pp+1).
    const int ps = 2 * ((195 * w) >> 3);
    const int pe = 2 * ((195 * (w + 1)) >> 3);

    const short8* wf = (const short8*)wfrag;            // idx = k*128 + half*64 + l
    const int vjoff = b * 16 + (h >> 1) * 256 + (h & 1) * 8;

    int cur_i = -1;
    short8 vi{};

    // Prologue: W fragments for the first pair-pair.
    short8 ca00 = wf[(size_t)(2 * ps) * 128 + l];        // k=2ps,  f 0..15
    short8 ca01 = wf[(size_t)(2 * ps) * 128 + 64 + l];   // k=2ps,  f 16..31
    short8 ca10 = wf[(size_t)(2 * ps + 1) * 128 + l];
    short8 ca11 = wf[(size_t)(2 * ps + 1) * 128 + 64 + l];

    for (int pp = ps; pp < pe; ++pp) {
        short8 na00{}, na01{}, na10{}, na11{};
        if (pp + 1 < pe) {                               // uniform prefetch branch
            const size_t k0 = (size_t)(2 * (pp + 1)) * 128;
            na00 = wf[k0 + l];
            na01 = wf[k0 + 64 + l];
            na10 = wf[k0 + 128 + l];
            na11 = wf[k0 + 192 + l];
        }
        const uint2 ij2 = *(const uint2*)(ijA + 2 * pp);
        float pf[2];
#pragma unroll
        for (int kk = 0; kk < 2; ++kk) {
            const unsigned int ij = kk ? ij2.y : ij2.x;
            const int i = (int)(ij & 0xffffu);
            const int joff = (int)(ij >> 16) << 10;
            if (i != cur_i) {                            // uniform; rare (i-major order)
                vi = *(const short8*)(embT + (i << 10) + l * 16);
                cur_i = i;
            }
            const short8 a0 = kk ? ca10 : ca00;
            const short8 a1 = kk ? ca11 : ca01;
            f32x4 acc0 = {};
            f32x4 acc1 = {};
            acc0 = __builtin_amdgcn_mfma_f32_16x16x32_bf16(a0, vi, acc0, 0, 0, 0); // f 0..15
            acc1 = __builtin_amdgcn_mfma_f32_16x16x32_bf16(a1, vi, acc1, 0, 0, 0); // f 16..31
            // lane's acc rows: f = 4h + r (acc0) and 16 + 4h + r (acc1)
            const char* vb = embT + joff + vjoff;
            const short4_t v0 = *(const short4_t*)(vb);
            const short4_t v1 = *(const short4_t*)(vb + 512);
            float p = acc0[0] * bf2f(v0[0]) + acc0[1] * bf2f(v0[1])
                    + acc0[2] * bf2f(v0[2]) + acc0[3] * bf2f(v0[3])
                    + acc1[0] * bf2f(v1[0]) + acc1[1] * bf2f(v1[1])
                    + acc1[2] * bf2f(v1[2]) + acc1[3] * bf2f(v1[3]);
            p += __shfl_xor(p, 16);                      // sum over h-groups
            p += __shfl_xor(p, 32);
            pf[kk] = p;
        }
        if (l < 16) {
            float2 st; st.x = pf[0]; st.y = pf[1];
            *(float2*)(out + (size_t)(b0 + b) * NK + 2 * pp) = st;
        }
        ca00 = na00; ca01 = na01; ca10 = na10; ca11 = na11;
    }
}

extern "C" void kernel_launch(void* const* d_in, const int* in_sizes, int n_in,
                              void* d_out, int out_size, void* d_ws, size_t ws_size,
                              hipStream_t stream) {
    const float* emb = (const float*)d_in[0];
    const float* W   = (const float*)d_in[1];
    float* out = (float*)d_out;
    unsigned short* wfrag = (unsigned short*)d_ws;       // 780*1024*2 B = 1.6 MB scratch

    wprep_kernel<<<dim3(NK), dim3(128), 0, stream>>>(W, wfrag);
    bil_kernel<<<dim3(8192 / BT), dim3(THREADS), 0, stream>>>(emb, wfrag, out);
}